// Round 2
// baseline (324.149 us; speedup 1.0000x reference)
//
#include <hip/hip_runtime.h>
#include <cstdint>
#include <cstddef>

typedef __bf16 bf16x8 __attribute__((ext_vector_type(8)));
typedef float  f32x4  __attribute__((ext_vector_type(4)));

#define TT 8192
#define EE 1024
#define NCHUNK 128
#define CLEN 64   // TT / NCHUNK

__device__ __forceinline__ unsigned short f2bf(float f) {
    union { float f; unsigned int u; } v; v.f = f;
    unsigned int r = v.u + 0x7FFFu + ((v.u >> 16) & 1u);
    return (unsigned short)(r >> 16);
}
__device__ __forceinline__ float b2f(unsigned short h) {
    union { unsigned int u; float f; } v; v.u = ((unsigned int)h) << 16; return v.f;
}

// ---------------------------------------------------------------------------
// Transpose W (E x E fp32, row-major) -> Wt (N x K bf16, row-major), 4 Ws.
// grid (32,32,4), block (32,8)
// ---------------------------------------------------------------------------
__global__ void wt_kernel(const float* __restrict__ Wk, const float* __restrict__ Wv,
                          const float* __restrict__ Wr, const float* __restrict__ Wo,
                          unsigned short* __restrict__ Tk, unsigned short* __restrict__ Tv,
                          unsigned short* __restrict__ Tr, unsigned short* __restrict__ To) {
    __shared__ float tile[32][33];
    const float* W; unsigned short* D;
    switch (blockIdx.z) {
        case 0:  W = Wk; D = Tk; break;
        case 1:  W = Wv; D = Tv; break;
        case 2:  W = Wr; D = Tr; break;
        default: W = Wo; D = To; break;
    }
    const int bx = blockIdx.x * 32, by = blockIdx.y * 32;
    const int tx = threadIdx.x, ty = threadIdx.y;
#pragma unroll
    for (int r = 0; r < 4; ++r)
        tile[ty + 8 * r][tx] = W[(size_t)(by + ty + 8 * r) * EE + bx + tx];
    __syncthreads();
#pragma unroll
    for (int r = 0; r < 4; ++r)
        D[(size_t)(bx + ty + 8 * r) * EE + by + tx] = f2bf(tile[tx][ty + 8 * r]);
}

// ---------------------------------------------------------------------------
// bf16 MFMA GEMM:  C[M,N] = A'[M,K] @ Bt[N,K]^T
//   MIXA: A' built on the fly = mix(x[t], x[t-1]/sx, tm)   (fp32 -> bf16)
//   else: A' = A (bf16, row-major)
//   MODE 0: C bf16 = acc;  MODE 1: C bf16 = sigmoid(acc);  MODE 2: C f32 = acc+Res
// M=8192, N=K=1024.  128x128 tile, BK=32, 256 threads, grid (64,8).
// ---------------------------------------------------------------------------
template <int MODE, bool MIXA>
__global__ __launch_bounds__(256) void gemm_bt(const unsigned short* __restrict__ A,
                                               const float* __restrict__ X,
                                               const float* __restrict__ SX,
                                               const float* __restrict__ TM,
                                               const unsigned short* __restrict__ Bt,
                                               const float* __restrict__ Res,
                                               void* __restrict__ Cout) {
    __shared__ __align__(16) unsigned short As[128 * 32];
    __shared__ __align__(16) unsigned short Bs[128 * 32];
    const int tid  = threadIdx.x;
    const int wave = tid >> 6, lane = tid & 63;
    const int wm = (wave >> 1) * 64, wn = (wave & 1) * 64;
    const int l15 = lane & 15, lq = lane >> 4;
    const int bm = blockIdx.x * 128, bn = blockIdx.y * 128;

    f32x4 acc[4][4] = {};

    for (int kt = 0; kt < 1024; kt += 32) {
        __syncthreads();
#pragma unroll
        for (int p = 0; p < 2; ++p) {
            const int li  = p * 256 + tid;
            const int row = li >> 2, q = li & 3;
            const int e0  = kt + q * 8;
            if (MIXA) {
                const int t = bm + row;
                const float* xr = X + (size_t)t * EE + e0;
                const float* pr = (t > 0) ? (X + (size_t)(t - 1) * EE + e0) : (SX + e0);
                float4 xa = *(const float4*)xr, xb = *(const float4*)(xr + 4);
                float4 pa = *(const float4*)pr, pb = *(const float4*)(pr + 4);
                float4 ma = *(const float4*)(TM + e0), mb = *(const float4*)(TM + e0 + 4);
                ushort4 lo, hi;
                lo.x = f2bf(fmaf(ma.x, xa.x - pa.x, pa.x));
                lo.y = f2bf(fmaf(ma.y, xa.y - pa.y, pa.y));
                lo.z = f2bf(fmaf(ma.z, xa.z - pa.z, pa.z));
                lo.w = f2bf(fmaf(ma.w, xa.w - pa.w, pa.w));
                hi.x = f2bf(fmaf(mb.x, xb.x - pb.x, pb.x));
                hi.y = f2bf(fmaf(mb.y, xb.y - pb.y, pb.y));
                hi.z = f2bf(fmaf(mb.z, xb.z - pb.z, pb.z));
                hi.w = f2bf(fmaf(mb.w, xb.w - pb.w, pb.w));
                *(ushort4*)(&As[row * 32 + q * 8])     = lo;
                *(ushort4*)(&As[row * 32 + q * 8 + 4]) = hi;
            } else {
                *(uint4*)(&As[row * 32 + q * 8]) =
                    *(const uint4*)(A + (size_t)(bm + row) * 1024 + e0);
            }
            *(uint4*)(&Bs[row * 32 + q * 8]) =
                *(const uint4*)(Bt + (size_t)(bn + row) * 1024 + e0);
        }
        __syncthreads();
        bf16x8 af[4], bfr[4];
#pragma unroll
        for (int i = 0; i < 4; ++i) {
            af[i]  = *(const bf16x8*)(&As[(wm + i * 16 + l15) * 32 + lq * 8]);
            bfr[i] = *(const bf16x8*)(&Bs[(wn + i * 16 + l15) * 32 + lq * 8]);
        }
#pragma unroll
        for (int i = 0; i < 4; ++i)
#pragma unroll
            for (int j = 0; j < 4; ++j)
                acc[i][j] = __builtin_amdgcn_mfma_f32_16x16x32_bf16(af[i], bfr[j], acc[i][j], 0, 0, 0);
    }

#pragma unroll
    for (int i = 0; i < 4; ++i)
#pragma unroll
        for (int j = 0; j < 4; ++j) {
            const int col = bn + wn + j * 16 + l15;
#pragma unroll
            for (int r = 0; r < 4; ++r) {
                const int row = bm + wm + i * 16 + lq * 4 + r;
                const size_t idx = (size_t)row * 1024 + col;
                const float val = acc[i][j][r];
                if (MODE == 2) {
                    ((float*)Cout)[idx] = val + Res[idx];
                } else if (MODE == 1) {
                    ((unsigned short*)Cout)[idx] = f2bf(1.f / (1.f + __expf(-val)));
                } else {
                    ((unsigned short*)Cout)[idx] = f2bf(val);
                }
            }
        }
}

// ---------------------------------------------------------------------------
// WKV pass A: per (chunk, channel) stabilized local summary
//   S = sum_i exp(w*(L-1-i)+k_i) * (v_i, 1), kept as (sa,sb,sp): S = s*e^sp
// grid NCHUNK*EE/256 blocks x 256
// ---------------------------------------------------------------------------
__global__ void wkv_pass_a(const unsigned short* __restrict__ k,
                           const unsigned short* __restrict__ v,
                           const float* __restrict__ td,
                           float* __restrict__ Sa, float* __restrict__ Sb, float* __restrict__ Sp) {
    const int gid = blockIdx.x * 256 + threadIdx.x;
    const int c = gid >> 10, e = gid & (EE - 1);
    const float w = -__expf(td[e]);
    float sa = 0.f, sb = 0.f, sp = -1e30f;
    const size_t base = (size_t)c * CLEN * EE + e;
    for (int i = 0; i < CLEN; ++i) {
        const size_t idx = base + (size_t)i * EE;
        const float kk = b2f(k[idx]), vv = b2f(v[idx]);
        const float q  = fmaf(w, (float)(CLEN - 1 - i), kk);
        const float p2 = fmaxf(sp, q);
        const float e1 = __expf(sp - p2), e2 = __expf(q - p2);
        sa = fmaf(e1, sa, e2 * vv);
        sb = fmaf(e1, sb, e2);
        sp = p2;
    }
    Sa[gid] = sa; Sb[gid] = sb; Sp[gid] = sp;
}

// ---------------------------------------------------------------------------
// WKV pass B: sequential exclusive scan over chunk summaries (per channel);
// also writes x[-1] and final (aa,bb,pp) to the output tail.
// grid 4 x 256
// ---------------------------------------------------------------------------
__global__ void wkv_pass_b(const float* __restrict__ aa, const float* __restrict__ bb,
                           const float* __restrict__ pp, const float* __restrict__ td,
                           const float* __restrict__ x,
                           const float* __restrict__ Sa, const float* __restrict__ Sb,
                           const float* __restrict__ Sp,
                           float* __restrict__ ina, float* __restrict__ inb,
                           float* __restrict__ inp, float* __restrict__ outTail) {
    const int e = blockIdx.x * 256 + threadIdx.x;   // 0..1023
    const float w  = -__expf(td[e]);
    const float wL = w * (float)CLEN;
    float a = aa[e], b = bb[e], p = pp[e];
    for (int c = 0; c < NCHUNK; ++c) {
        const int idx = c * EE + e;
        ina[idx] = a; inb[idx] = b; inp[idx] = p;
        const float sa = Sa[idx], sb = Sb[idx], sp = Sp[idx];
        const float pw = p + wL;
        const float p2 = fmaxf(pw, sp);
        const float e1 = __expf(pw - p2), e2 = __expf(sp - p2);
        a = fmaf(e1, a, e2 * sa);
        b = fmaf(e1, b, e2 * sb);
        p = p2;
    }
    outTail[e]          = x[(size_t)(TT - 1) * EE + e];   // x[-1]
    outTail[EE + e]     = a;                              // aa_f
    outTail[2 * EE + e] = b;                              // bb_f
    outTail[3 * EE + e] = p;                              // pp_f
}

// ---------------------------------------------------------------------------
// WKV pass C: replay each chunk from its incoming state; ry holds sigmoid(r)
// on input and is overwritten in place with y = sigmoid(r)*wkv (bf16).
// grid NCHUNK*EE/256 blocks x 256
// ---------------------------------------------------------------------------
__global__ void wkv_pass_c(const unsigned short* __restrict__ k,
                           const unsigned short* __restrict__ v,
                           const float* __restrict__ tf, const float* __restrict__ td,
                           const float* __restrict__ ina, const float* __restrict__ inb,
                           const float* __restrict__ inp,
                           unsigned short* ry) {
    const int gid = blockIdx.x * 256 + threadIdx.x;
    const int c = gid >> 10, e = gid & (EE - 1);
    const float w = -__expf(td[e]);
    const float u = tf[e];
    float a = ina[gid], b = inb[gid], p = inp[gid];
    const size_t base = (size_t)c * CLEN * EE + e;
    for (int i = 0; i < CLEN; ++i) {
        const size_t idx = base + (size_t)i * EE;
        const float kk = b2f(k[idx]), vv = b2f(v[idx]);
        const float rr = b2f(ry[idx]);
        const float ww = u + kk;
        const float pq = fmaxf(p, ww);
        const float e1 = __expf(p - pq), e2 = __expf(ww - pq);
        const float wkv = fmaf(e1, a, e2 * vv) / fmaf(e1, b, e2);
        ry[idx] = f2bf(rr * wkv);
        const float ww2 = w + p;
        const float p2  = fmaxf(ww2, kk);
        const float e1b = __expf(ww2 - p2), e2b = __expf(kk - p2);
        a = fmaf(e1b, a, e2b * vv);
        b = fmaf(e1b, b, e2b);
        p = p2;
    }
}

// ---------------------------------------------------------------------------
extern "C" void kernel_launch(void* const* d_in, const int* in_sizes, int n_in,
                              void* d_out, int out_size, void* d_ws, size_t ws_size,
                              hipStream_t stream) {
    const float* x   = (const float*)d_in[0];
    const float* sx  = (const float*)d_in[1];
    const float* aa  = (const float*)d_in[2];
    const float* bb  = (const float*)d_in[3];
    const float* pp  = (const float*)d_in[4];
    const float* tf  = (const float*)d_in[5];
    const float* td  = (const float*)d_in[6];
    const float* tmk = (const float*)d_in[7];
    const float* tmv = (const float*)d_in[8];
    const float* tmr = (const float*)d_in[9];
    const float* Wk  = (const float*)d_in[10];
    const float* Wv  = (const float*)d_in[11];
    const float* Wr  = (const float*)d_in[12];
    const float* Wo  = (const float*)d_in[13];
    float* out = (float*)d_out;

    // --- workspace layout: 27 MB total ---
    char* ws = (char*)d_ws;
    const size_t MB = 1ull << 20;
    unsigned short* Wkt = (unsigned short*)(ws + 0 * MB);   // 2 MB each
    unsigned short* Wvt = (unsigned short*)(ws + 2 * MB);
    unsigned short* Wrt = (unsigned short*)(ws + 4 * MB);
    unsigned short* Wot = (unsigned short*)(ws + 6 * MB);
    unsigned short* ry  = (unsigned short*)(ws + 8 * MB);   // 16 MB: sigmoid(r), then y
    const size_t QK = (size_t)NCHUNK * EE * sizeof(float);  // 512 KB
    float* Sa  = (float*)(ws + 24 * MB);
    float* Sb  = (float*)(ws + 24 * MB + QK);
    float* Sp  = (float*)(ws + 24 * MB + 2 * QK);
    float* ina = (float*)(ws + 24 * MB + 3 * QK);
    float* inb = (float*)(ws + 24 * MB + 4 * QK);
    float* inp = (float*)(ws + 24 * MB + 5 * QK);

    // --- d_out doubles as scratch for bf16 k and v until the final GEMM ---
    unsigned short* kf = (unsigned short*)d_out;                        // 16 MB
    unsigned short* vf = (unsigned short*)d_out + (size_t)TT * EE;      // 16 MB

    // 1. W transposes -> bf16
    wt_kernel<<<dim3(32, 32, 4), dim3(32, 8), 0, stream>>>(Wk, Wv, Wr, Wo, Wkt, Wvt, Wrt, Wot);
    // 2-4. k, v, sigmoid(r) GEMMs with fused token-shift mix
    gemm_bt<0, true><<<dim3(64, 8), 256, 0, stream>>>(nullptr, x, sx, tmk, Wkt, nullptr, kf);
    gemm_bt<0, true><<<dim3(64, 8), 256, 0, stream>>>(nullptr, x, sx, tmv, Wvt, nullptr, vf);
    gemm_bt<1, true><<<dim3(64, 8), 256, 0, stream>>>(nullptr, x, sx, tmr, Wrt, nullptr, ry);
    // 5-7. chunked WKV scan
    wkv_pass_a<<<(NCHUNK * EE) / 256, 256, 0, stream>>>(kf, vf, td, Sa, Sb, Sp);
    wkv_pass_b<<<4, 256, 0, stream>>>(aa, bb, pp, td, x, Sa, Sb, Sp, ina, inb, inp,
                                      out + (size_t)TT * EE);
    wkv_pass_c<<<(NCHUNK * EE) / 256, 256, 0, stream>>>(kf, vf, tf, td, ina, inb, inp, ry);
    // 8. out = x + y @ Wo   (overwrites the k/v scratch in d_out)
    gemm_bt<2, false><<<dim3(64, 8), 256, 0, stream>>>(ry, nullptr, nullptr, nullptr, Wot, x, out);
}